// Round 8
// baseline (201.240 us; speedup 1.0000x reference)
//
#include <hip/hip_runtime.h>

// ClebschCombiningSingleUnrolled: out[mu] += mult * X1[m1] * X2[m2] over N*D points.
// M=9, K=100, P = N*D = 1048576.
//
// R8: MEASUREMENT ROUND. Kernel byte-identical to R7 (dense-bilinear register
// kernel, parallel prep). cleb_dense is launched 4x (idempotent overwrite of
// the same output) so its standalone duration X is recoverable from the dur_us
// delta vs R7: X = (dur_R8 - dur_R7)/3. The harness's ~86us restore/poison
// overhead and the ~41us top-5 cutoff have hidden cleb's counters since R5;
// this round buys the number that decides whether R9 attacks serialization
// (X~35) or declares near-floor (X~18).

#define M_CH 9
#define CSIZE 768            // 729 padded

typedef float v2f __attribute__((ext_vector_type(2)));

__global__ __launch_bounds__(128) void prep_kernel(
    const int* __restrict__ m1, const int* __restrict__ m2,
    const int* __restrict__ mu, const float* __restrict__ mult,
    int K, float* __restrict__ Cd) {
    const int t = threadIdx.x;
    for (int i = t; i < CSIZE; i += 128) Cd[i] = 0.f;
    __syncthreads();                       // orders block's global writes
    if (t < K) {
        const int idx = (m1[t] * M_CH + m2[t]) * M_CH + mu[t];
        atomicAdd(&Cd[idx], mult[t]);      // duplicates accumulate
    }
}

__global__ __launch_bounds__(64) void cleb_dense(
    const float* __restrict__ X1, const float* __restrict__ X2,
    const float* __restrict__ Cd, float* __restrict__ out, int P) {
    const int lane = threadIdx.x;
    const size_t base = (size_t)blockIdx.x * 256 + (size_t)lane * 4;

    // 18 independent 16B input loads issued up front
    v2f x1[M_CH][2], x2[M_CH][2];
    #pragma unroll
    for (int m = 0; m < M_CH; ++m) {
        const float4 a = *(const float4*)(X1 + (size_t)m * P + base);
        const float4 b = *(const float4*)(X2 + (size_t)m * P + base);
        x1[m][0] = (v2f){a.x, a.y}; x1[m][1] = (v2f){a.z, a.w};
        x2[m][0] = (v2f){b.x, b.y}; x2[m][1] = (v2f){b.z, b.w};
    }

    v2f acc[M_CH][2];
    #pragma unroll
    for (int m = 0; m < M_CH; ++m) { acc[m][0] = (v2f)0.f; acc[m][1] = (v2f)0.f; }

    #pragma unroll
    for (int p1 = 0; p1 < M_CH; ++p1) {
        #pragma unroll
        for (int p2 = 0; p2 < M_CH; ++p2) {
            const v2f prod0 = x1[p1][0] * x2[p2][0];     // v_pk_mul_f32
            const v2f prod1 = x1[p1][1] * x2[p2][1];
            #pragma unroll
            for (int m = 0; m < M_CH; ++m) {
                // compile-time idx + uniform pointer -> scalar (s_load) fetch
                const float c = Cd[(p1 * M_CH + p2) * M_CH + m];
                const v2f cv = (v2f){c, c};
                acc[m][0] = __builtin_elementwise_fma(cv, prod0, acc[m][0]);
                acc[m][1] = __builtin_elementwise_fma(cv, prod1, acc[m][1]);
            }
        }
    }

    #pragma unroll
    for (int m = 0; m < M_CH; ++m) {
        float4 r;
        r.x = acc[m][0].x; r.y = acc[m][0].y;
        r.z = acc[m][1].x; r.w = acc[m][1].y;
        *(float4*)(out + (size_t)m * P + base) = r;
    }
}

extern "C" void kernel_launch(void* const* d_in, const int* in_sizes, int n_in,
                              void* d_out, int out_size, void* d_ws, size_t ws_size,
                              hipStream_t stream) {
    const float* X1   = (const float*)d_in[0];
    const float* X2   = (const float*)d_in[1];
    const int*   m1   = (const int*)d_in[2];
    const int*   m2   = (const int*)d_in[3];
    const int*   mu   = (const int*)d_in[4];
    const float* mult = (const float*)d_in[5];
    float* out = (float*)d_out;
    float* Cd  = (float*)d_ws;

    const int K = in_sizes[2];                 // 100
    const int P = in_sizes[0] / M_CH;          // 1048576

    prep_kernel<<<1, 128, 0, stream>>>(m1, m2, mu, mult, K, Cd);
    // 4x identical launches (idempotent): X = (dur_R8 - dur_R7)/3
    cleb_dense<<<P / 256, 64, 0, stream>>>(X1, X2, Cd, out, P);
    cleb_dense<<<P / 256, 64, 0, stream>>>(X1, X2, Cd, out, P);
    cleb_dense<<<P / 256, 64, 0, stream>>>(X1, X2, Cd, out, P);
    cleb_dense<<<P / 256, 64, 0, stream>>>(X1, X2, Cd, out, P);
}